// Round 2
// baseline (727.846 us; speedup 1.0000x reference)
//
#include <hip/hip_runtime.h>
#include <math.h>

#define K_DIM 512
#define N_DIM 512
#define NLEAF 2048   // numpy pairwise leaves of 128 over 2^18 elements
#define BM 128
#define BN 128
#define BK 16
#define NCHUNK (K_DIM / BK)   // 32

// ws float layout: [0]=mu, [1]=gamma, [16..16+2047]=leaf sums, [2064..4111]=leaf abs-sums
#define WS_LEAFS 16
#define WS_LEAFA (16 + NLEAF)

// ---------------------------------------------------------------------------
// NUMERICS CONTRACT (validated round 3, absmax==0.0 — DO NOT CHANGE):
//  mu/gamma: numpy fp32 pairwise tree — 2048 leaves of 128 elems, each leaf
//    via 8-accumulator pattern + combine ((r0+r1)+(r2+r3))+((r4+r5)+(r6+r7)),
//    then perfect binary tree (left+right), scale by 2^-18.
//  eff_w = fl(fl(w + fl(sign(fl(w-mu)) - w)) * gamma)
//  y: per-output single fp32 accumulator, fmaf chain, k STRICTLY ascending.
//  epilogue: yb=y+bias; cl=clip; rr=rintf(cl*7); q=rr/7; out=yb+(q-yb).
// ---------------------------------------------------------------------------

// Leaf sums: one thread per leaf, sequential 8-acc pattern (bit-exact order).
__global__ void leaf_kernel(const float* __restrict__ w, float* __restrict__ ws) {
  const int leaf = blockIdx.x * blockDim.x + threadIdx.x;  // 2048 total
  const float* p = w + leaf * 128;
  float rs[8], ra[8];
  #pragma unroll
  for (int j = 0; j < 8; ++j) { const float v = p[j]; rs[j] = v; ra[j] = fabsf(v); }
  for (int i = 8; i < 128; i += 8) {
    #pragma unroll
    for (int j = 0; j < 8; ++j) { const float v = p[i + j]; rs[j] += v; ra[j] += fabsf(v); }
  }
  ws[WS_LEAFS + leaf] = ((rs[0] + rs[1]) + (rs[2] + rs[3])) + ((rs[4] + rs[5]) + (rs[6] + rs[7]));
  ws[WS_LEAFA + leaf] = ((ra[0] + ra[1]) + (ra[2] + ra[3])) + ((ra[4] + ra[5]) + (ra[6] + ra[7]));
}

// Binary-tree combine of the 2048 leaf partials, exact numpy pairing.
__global__ void tree_kernel(float* __restrict__ ws) {
  __shared__ float bufS[4096];
  __shared__ float bufA[4096];
  const int t = threadIdx.x;  // 256 threads, 1 block
  for (int i = t; i < NLEAF; i += 256) {
    bufS[i] = ws[WS_LEAFS + i];
    bufA[i] = ws[WS_LEAFA + i];
  }
  __syncthreads();
  int src = 0, n = NLEAF;
  while (n > 1) {
    const int dst = src + n;
    n >>= 1;
    for (int i = t; i < n; i += 256) {
      bufS[dst + i] = bufS[src + 2 * i] + bufS[src + 2 * i + 1];
      bufA[dst + i] = bufA[src + 2 * i] + bufA[src + 2 * i + 1];
    }
    __syncthreads();
    src = dst;
  }
  if (t == 0) {
    ws[0] = bufS[src] * (1.0f / 262144.0f);  // exact pow2 scale == np divide
    ws[1] = bufA[src] * (1.0f / 262144.0f);
  }
}

// 128x128 block tile, 256 threads, 8x8 micro-tile (2x2 quadrants of 4x4).
// BK=16, register-staged DOUBLE-BUFFERED LDS: loads for chunk c+1 issue
// before compute of chunk c (≈2048 FMA-issue cycles cover the ~600cy load
// latency); vmcnt wait lands at the ds_write, not at the barrier. ONE
// barrier per chunk. Summation order unchanged (k strictly ascending).
__global__ __launch_bounds__(256, 3) void gemm_kernel(
    const float* __restrict__ x, const float* __restrict__ w,
    const float* __restrict__ bias, const float* __restrict__ ws,
    float* __restrict__ out) {
  __shared__ float As[2][BM][BK];      // 2 x 128 x 16 dwords = 16 KB (rows 64B-aligned)
  __shared__ float Bs[2][BK][BN + 4];  // 2 x 16 x 132 dwords = 16.9 KB

  const float mu = ws[0];
  const float gamma = ws[1];
  const int t = threadIdx.x;
  const int tx = t & 15;   // col group: cols {tx*4..+3} and {64+tx*4..+3}
  const int ty = t >> 4;   // row group: rows {ty*4..+3} and {64+ty*4..+3}
  const int rowBase = blockIdx.x * BM;
  const int colBase = blockIdx.y * BN;

  // staging coords: A = 2 float4/thread (4 lanes/row, 64B segments);
  //                 B = 2 float4/thread (32 lanes/row, 512B segments)
  const int ar = t >> 2;          // 0..63  (rows ar, ar+64)
  const int ak4 = (t & 3) * 4;    // k within chunk
  const int bk = t >> 5;          // 0..7   (k rows bk, bk+8)
  const int bn4 = (t & 31) * 4;   // col within tile

  const float* xA0 = x + (size_t)(rowBase + ar) * K_DIM + ak4;
  const float* xA1 = x + (size_t)(rowBase + ar + 64) * K_DIM + ak4;
  const float* wB0 = w + (size_t)bk * N_DIM + colBase + bn4;
  const float* wB1 = w + (size_t)(bk + 8) * N_DIM + colBase + bn4;

  float acc[2][2][4][4];
  #pragma unroll
  for (int h = 0; h < 2; ++h)
    #pragma unroll
    for (int g = 0; g < 2; ++g)
      #pragma unroll
      for (int i = 0; i < 4; ++i)
        #pragma unroll
        for (int j = 0; j < 4; ++j) acc[h][g][i][j] = 0.0f;

  // faithful STE weight DAG (exact fp32 op order — validated)
  auto ste4 = [&](float4 v) -> float4 {
    float4 e;
    const float* vi = &v.x;
    float* ei = &e.x;
    #pragma unroll
    for (int c = 0; c < 4; ++c) {
      const float wv = vi[c];
      const float wc = wv - mu;
      const float bin = (wc > 0.0f) ? 1.0f : ((wc < 0.0f) ? -1.0f : 0.0f);
      const float ste = wv + (bin - wv);
      ei[c] = ste * gamma;
    }
    return e;
  };

  auto compute = [&](int cur) {
    #pragma unroll
    for (int kg = 0; kg < 4; ++kg) {  // 4 groups of 4 k
      float4 a0[4], a1[4];
      #pragma unroll
      for (int i = 0; i < 4; ++i) {
        a0[i] = *(const float4*)&As[cur][ty * 4 + i][kg * 4];
        a1[i] = *(const float4*)&As[cur][64 + ty * 4 + i][kg * 4];
      }
      #pragma unroll
      for (int kk = 0; kk < 4; ++kk) {  // k ascending within group
        const float4 b0 = *(const float4*)&Bs[cur][kg * 4 + kk][tx * 4];
        const float4 b1 = *(const float4*)&Bs[cur][kg * 4 + kk][64 + tx * 4];
        const float* b0p = &b0.x;
        const float* b1p = &b1.x;
        #pragma unroll
        for (int i = 0; i < 4; ++i) {
          const float av0 = (&a0[i].x)[kk];
          const float av1 = (&a1[i].x)[kk];
          #pragma unroll
          for (int j = 0; j < 4; ++j) {
            acc[0][0][i][j] = fmaf(av0, b0p[j], acc[0][0][i][j]);
            acc[0][1][i][j] = fmaf(av0, b1p[j], acc[0][1][i][j]);
            acc[1][0][i][j] = fmaf(av1, b0p[j], acc[1][0][i][j]);
            acc[1][1][i][j] = fmaf(av1, b1p[j], acc[1][1][i][j]);
          }
        }
      }
    }
  };

  // ---- prologue: stage chunk 0 into buffer 0 ----
  {
    const float4 ra0 = *(const float4*)xA0;
    const float4 ra1 = *(const float4*)xA1;
    const float4 rb0 = *(const float4*)wB0;
    const float4 rb1 = *(const float4*)wB1;
    *(float4*)&As[0][ar][ak4] = ra0;
    *(float4*)&As[0][ar + 64][ak4] = ra1;
    *(float4*)&Bs[0][bk][bn4] = ste4(rb0);
    *(float4*)&Bs[0][bk + 8][bn4] = ste4(rb1);
  }
  __syncthreads();

  // ---- main loop: compute chunk c while chunk c+1 is in flight ----
  for (int c = 0; c < NCHUNK - 1; ++c) {
    const int cur = c & 1;
    const int kc1 = (c + 1) * BK;
    // issue next-chunk global loads BEFORE compute (latency hidden)
    const float4 ra0 = *(const float4*)(xA0 + kc1);
    const float4 ra1 = *(const float4*)(xA1 + kc1);
    const float4 rb0 = *(const float4*)(wB0 + (size_t)kc1 * N_DIM);
    const float4 rb1 = *(const float4*)(wB1 + (size_t)kc1 * N_DIM);

    compute(cur);

    const int nxt = cur ^ 1;
    *(float4*)&As[nxt][ar][ak4] = ra0;
    *(float4*)&As[nxt][ar + 64][ak4] = ra1;
    *(float4*)&Bs[nxt][bk][bn4] = ste4(rb0);
    *(float4*)&Bs[nxt][bk + 8][bn4] = ste4(rb1);
    __syncthreads();
  }
  compute((NCHUNK - 1) & 1);  // last chunk, no prefetch

  // faithful fp32 epilogue (unchanged DAG from validated round 3)
  #pragma unroll
  for (int h = 0; h < 2; ++h)
    #pragma unroll
    for (int i = 0; i < 4; ++i) {
      const size_t row = (size_t)(rowBase + h * 64 + ty * 4 + i);
      #pragma unroll
      for (int g = 0; g < 2; ++g) {
        const int col = colBase + g * 64 + tx * 4;
        float4 o;
        float* op = &o.x;
        #pragma unroll
        for (int j = 0; j < 4; ++j) {
          const float yb = acc[h][g][i][j] + bias[col + j];
          const float cl = fminf(fmaxf(yb, -1.0f), 1.0f);
          const float t7 = cl * 7.0f;
          const float rr = rintf(t7);
          const float q = rr / 7.0f;
          op[j] = yb + (q - yb);
        }
        *(float4*)&out[row * N_DIM + col] = o;
      }
    }
}

extern "C" void kernel_launch(void* const* d_in, const int* in_sizes, int n_in,
                              void* d_out, int out_size, void* d_ws, size_t ws_size,
                              hipStream_t stream) {
  const float* x = (const float*)d_in[0];
  const float* w = (const float*)d_in[1];
  const float* bias = (const float*)d_in[2];
  float* out = (float*)d_out;
  float* ws = (float*)d_ws;  // uses 16448 bytes

  const int M = in_sizes[0] / K_DIM;  // 65536 rows

  leaf_kernel<<<NLEAF / 256, 256, 0, stream>>>(w, ws);
  tree_kernel<<<1, 256, 0, stream>>>(ws);
  gemm_kernel<<<dim3(M / BM, N_DIM / BN), 256, 0, stream>>>(x, w, bias, ws, out);
}

// Round 3
// 615.608 us; speedup vs baseline: 1.1823x; 1.1823x over previous
//
#include <hip/hip_runtime.h>
#include <math.h>

#define K_DIM 512
#define N_DIM 512
#define NLEAF 2048   // numpy pairwise leaves of 128 over 2^18 elements
#define BM 128
#define BN 128
#define BK 32

// ws float layout: [0]=mu, [1]=gamma, [16..2063]=leaf sums, [2064..4111]=leaf abs-sums,
//                  [4112..4112+262143]=precomputed effective weights (fast path only)
#define WS_LEAFS 16
#define WS_LEAFA (16 + NLEAF)
#define WS_EFF 4112

#define GLOBAL_AS __attribute__((address_space(1)))
#define LDS_AS __attribute__((address_space(3)))

// ---------------------------------------------------------------------------
// NUMERICS CONTRACT (validated, absmax==0.0 — DO NOT CHANGE):
//  mu/gamma: numpy fp32 pairwise tree — 2048 leaves of 128 elems, each leaf
//    via 8-accumulator pattern + combine ((r0+r1)+(r2+r3))+((r4+r5)+(r6+r7)),
//    then perfect binary tree (left+right), scale by 2^-18.
//  eff_w = fl(fl(w + fl(sign(fl(w-mu)) - w)) * gamma)   (same DAG whether
//    computed fused in-gemm or once in binarize_kernel — identical per-element
//    fp32 op sequence, same compile flags => bit-identical)
//  y: per-output single fp32 accumulator, fmaf chain, k STRICTLY ascending.
//  epilogue: yb=y+bias; cl=clip; rr=rintf(cl*7); q=rr/7; out=yb+(q-yb).
// ---------------------------------------------------------------------------

// Leaf sums: one thread per leaf, sequential 8-acc pattern (bit-exact order).
__global__ void leaf_kernel(const float* __restrict__ w, float* __restrict__ ws) {
  const int leaf = blockIdx.x * blockDim.x + threadIdx.x;  // 2048 total
  const float* p = w + leaf * 128;
  float rs[8], ra[8];
  #pragma unroll
  for (int j = 0; j < 8; ++j) { const float v = p[j]; rs[j] = v; ra[j] = fabsf(v); }
  for (int i = 8; i < 128; i += 8) {
    #pragma unroll
    for (int j = 0; j < 8; ++j) { const float v = p[i + j]; rs[j] += v; ra[j] += fabsf(v); }
  }
  ws[WS_LEAFS + leaf] = ((rs[0] + rs[1]) + (rs[2] + rs[3])) + ((rs[4] + rs[5]) + (rs[6] + rs[7]));
  ws[WS_LEAFA + leaf] = ((ra[0] + ra[1]) + (ra[2] + ra[3])) + ((ra[4] + ra[5]) + (ra[6] + ra[7]));
}

// Binary-tree combine of the 2048 leaf partials, exact numpy pairing.
__global__ void tree_kernel(float* __restrict__ ws) {
  __shared__ float bufS[4096];
  __shared__ float bufA[4096];
  const int t = threadIdx.x;  // 256 threads, 1 block
  for (int i = t; i < NLEAF; i += 256) {
    bufS[i] = ws[WS_LEAFS + i];
    bufA[i] = ws[WS_LEAFA + i];
  }
  __syncthreads();
  int src = 0, n = NLEAF;
  while (n > 1) {
    const int dst = src + n;
    n >>= 1;
    for (int i = t; i < n; i += 256) {
      bufS[dst + i] = bufS[src + 2 * i] + bufS[src + 2 * i + 1];
      bufA[dst + i] = bufA[src + 2 * i] + bufA[src + 2 * i + 1];
    }
    __syncthreads();
    src = dst;
  }
  if (t == 0) {
    ws[0] = bufS[src] * (1.0f / 262144.0f);  // exact pow2 scale == np divide
    ws[1] = bufA[src] * (1.0f / 262144.0f);
  }
}

// Precompute eff_w once (0.26M elems) instead of 33.5M fused transforms
// inside the gemm. Exact same per-element fp32 DAG as the fused path.
__global__ void binarize_kernel(const float* __restrict__ w, float* __restrict__ ws) {
  const float mu = ws[0];
  const float gamma = ws[1];
  const int i = (blockIdx.x * 256 + threadIdx.x) * 4;
  const float4 v = *(const float4*)&w[i];
  float4 e;
  const float* vi = &v.x;
  float* ei = &e.x;
  #pragma unroll
  for (int c = 0; c < 4; ++c) {
    const float wv = vi[c];
    const float wc = wv - mu;
    const float bin = (wc > 0.0f) ? 1.0f : ((wc < 0.0f) ? -1.0f : 0.0f);
    const float ste = wv + (bin - wv);
    ei[c] = ste * gamma;
  }
  *(float4*)&ws[WS_EFF + i] = e;
}

// FAST PATH: 128x128 tile, 256 threads, 8x8 micro-tile (round-0 structure).
// B staged via global_load_lds width-16 DMA into LINEAR Bs (stride 128):
//  - no VGPR round-trip, no B ds_writes, no in-loop STE VALU
//  - compute B-reads: 16 distinct addrs spanning 64 consecutive dwords,
//    row term k*128 == 0 mod 32 -> 2 addrs/bank = conflict-free.
// A reg-staged into padded As (stride 36, 2-way broadcast reads = free).
__global__ __launch_bounds__(256, 4) void gemm_kernel_pre(
    const float* __restrict__ x, const float* __restrict__ eff,
    const float* __restrict__ bias, float* __restrict__ out) {
  __shared__ float As[BM][BK + 4];  // 128 x 36 dwords (16B-aligned rows)
  __shared__ float Bs[BK][BN];      // 32 x 128 dwords, LINEAR for DMA

  const int t = threadIdx.x;
  const int tx = t & 15;   // col group: cols {tx*4..+3} and {64+tx*4..+3}
  const int ty = t >> 4;   // row group: rows {ty*4..+3} and {64+ty*4..+3}
  const int rowBase = blockIdx.x * BM;
  const int colBase = blockIdx.y * BN;

  float acc[2][2][4][4];
  #pragma unroll
  for (int h = 0; h < 2; ++h)
    #pragma unroll
    for (int g = 0; g < 2; ++g)
      #pragma unroll
      for (int i = 0; i < 4; ++i)
        #pragma unroll
        for (int j = 0; j < 4; ++j) acc[h][g][i][j] = 0.0f;

  for (int kc = 0; kc < K_DIM; kc += BK) {  // 16 chunks, ascending k
    // B: async DMA, 4 x 16B per thread, linear LDS dest = chunk-linear order
    #pragma unroll
    for (int p = 0; p < 4; ++p) {
      const int off = p * 1024 + t * 4;   // dword offset within 32x128 chunk
      const int r = off >> 7;             // row 0..31
      const int cdw = off & 127;          // col dword 0..127
      const float* gsrc = &eff[(size_t)(kc + r) * N_DIM + colBase + cdw];
      float* ldst = &Bs[0][0] + off;
      __builtin_amdgcn_global_load_lds((const GLOBAL_AS void*)gsrc,
                                       (LDS_AS void*)ldst, 16, 0, 0);
    }
    // A: reg-staged, coalesced (8 lanes * 16B = 128B per row), padded LDS
    #pragma unroll
    for (int p = 0; p < 4; ++p) {
      const int r = (t >> 3) + 32 * p;
      const int k4 = (t & 7) * 4;
      const float4 v = *(const float4*)&x[(size_t)(rowBase + r) * K_DIM + kc + k4];
      *(float4*)&As[r][k4] = v;
    }
    __syncthreads();

    #pragma unroll
    for (int kg = 0; kg < 8; ++kg) {  // 8 groups of 4 k
      float4 a0[4], a1[4];
      #pragma unroll
      for (int i = 0; i < 4; ++i) {
        a0[i] = *(const float4*)&As[ty * 4 + i][kg * 4];
        a1[i] = *(const float4*)&As[64 + ty * 4 + i][kg * 4];
      }
      #pragma unroll
      for (int kk = 0; kk < 4; ++kk) {  // k ascending within group
        const float4 b0 = *(const float4*)&Bs[kg * 4 + kk][tx * 4];
        const float4 b1 = *(const float4*)&Bs[kg * 4 + kk][64 + tx * 4];
        const float* b0p = &b0.x;
        const float* b1p = &b1.x;
        #pragma unroll
        for (int i = 0; i < 4; ++i) {
          const float av0 = (&a0[i].x)[kk];
          const float av1 = (&a1[i].x)[kk];
          #pragma unroll
          for (int j = 0; j < 4; ++j) {
            acc[0][0][i][j] = fmaf(av0, b0p[j], acc[0][0][i][j]);
            acc[0][1][i][j] = fmaf(av0, b1p[j], acc[0][1][i][j]);
            acc[1][0][i][j] = fmaf(av1, b0p[j], acc[1][0][i][j]);
            acc[1][1][i][j] = fmaf(av1, b1p[j], acc[1][1][i][j]);
          }
        }
      }
    }
    __syncthreads();
  }

  // faithful fp32 epilogue (unchanged DAG)
  #pragma unroll
  for (int h = 0; h < 2; ++h)
    #pragma unroll
    for (int i = 0; i < 4; ++i) {
      const size_t row = (size_t)(rowBase + h * 64 + ty * 4 + i);
      #pragma unroll
      for (int g = 0; g < 2; ++g) {
        const int col = colBase + g * 64 + tx * 4;
        float4 o;
        float* op = &o.x;
        #pragma unroll
        for (int j = 0; j < 4; ++j) {
          const float yb = acc[h][g][i][j] + bias[col + j];
          const float cl = fminf(fmaxf(yb, -1.0f), 1.0f);
          const float t7 = cl * 7.0f;
          const float rr = rintf(t7);
          const float q = rr / 7.0f;
          op[j] = yb + (q - yb);
        }
        *(float4*)&out[row * N_DIM + col] = o;
      }
    }
}

// FALLBACK (ws too small for eff_w): exact round-0 fused gemm, validated 434us.
__global__ __launch_bounds__(256, 4) void gemm_kernel_fused(
    const float* __restrict__ x, const float* __restrict__ w,
    const float* __restrict__ bias, const float* __restrict__ ws,
    float* __restrict__ out) {
  __shared__ float As[BM][BK + 4];
  __shared__ float Bs[BK][BN + 4];

  const float mu = ws[0];
  const float gamma = ws[1];
  const int t = threadIdx.x;
  const int tx = t & 15;
  const int ty = t >> 4;
  const int rowBase = blockIdx.x * BM;
  const int colBase = blockIdx.y * BN;

  float acc[2][2][4][4];
  #pragma unroll
  for (int h = 0; h < 2; ++h)
    #pragma unroll
    for (int g = 0; g < 2; ++g)
      #pragma unroll
      for (int i = 0; i < 4; ++i)
        #pragma unroll
        for (int j = 0; j < 4; ++j) acc[h][g][i][j] = 0.0f;

  for (int kc = 0; kc < K_DIM; kc += BK) {
    #pragma unroll
    for (int p = 0; p < 4; ++p) {
      const int r = (t >> 3) + 32 * p;
      const int k4 = (t & 7) * 4;
      const float4 v = *(const float4*)&x[(size_t)(rowBase + r) * K_DIM + kc + k4];
      *(float4*)&As[r][k4] = v;
    }
    #pragma unroll
    for (int p = 0; p < 4; ++p) {
      const int kk = (t >> 5) + 8 * p;
      const int n4 = (t & 31) * 4;
      const float4 v = *(const float4*)&w[(size_t)(kc + kk) * N_DIM + colBase + n4];
      float4 e;
      const float* vi = &v.x;
      float* ei = &e.x;
      #pragma unroll
      for (int c = 0; c < 4; ++c) {
        const float wv = vi[c];
        const float wc = wv - mu;
        const float bin = (wc > 0.0f) ? 1.0f : ((wc < 0.0f) ? -1.0f : 0.0f);
        const float ste = wv + (bin - wv);
        ei[c] = ste * gamma;
      }
      *(float4*)&Bs[kk][n4] = e;
    }
    __syncthreads();

    #pragma unroll
    for (int kg = 0; kg < 8; ++kg) {
      float4 a0[4], a1[4];
      #pragma unroll
      for (int i = 0; i < 4; ++i) {
        a0[i] = *(const float4*)&As[ty * 4 + i][kg * 4];
        a1[i] = *(const float4*)&As[64 + ty * 4 + i][kg * 4];
      }
      #pragma unroll
      for (int kk = 0; kk < 4; ++kk) {
        const float4 b0 = *(const float4*)&Bs[kg * 4 + kk][tx * 4];
        const float4 b1 = *(const float4*)&Bs[kg * 4 + kk][64 + tx * 4];
        const float* b0p = &b0.x;
        const float* b1p = &b1.x;
        #pragma unroll
        for (int i = 0; i < 4; ++i) {
          const float av0 = (&a0[i].x)[kk];
          const float av1 = (&a1[i].x)[kk];
          #pragma unroll
          for (int j = 0; j < 4; ++j) {
            acc[0][0][i][j] = fmaf(av0, b0p[j], acc[0][0][i][j]);
            acc[0][1][i][j] = fmaf(av0, b1p[j], acc[0][1][i][j]);
            acc[1][0][i][j] = fmaf(av1, b0p[j], acc[1][0][i][j]);
            acc[1][1][i][j] = fmaf(av1, b1p[j], acc[1][1][i][j]);
          }
        }
      }
    }
    __syncthreads();
  }

  #pragma unroll
  for (int h = 0; h < 2; ++h)
    #pragma unroll
    for (int i = 0; i < 4; ++i) {
      const size_t row = (size_t)(rowBase + h * 64 + ty * 4 + i);
      #pragma unroll
      for (int g = 0; g < 2; ++g) {
        const int col = colBase + g * 64 + tx * 4;
        float4 o;
        float* op = &o.x;
        #pragma unroll
        for (int j = 0; j < 4; ++j) {
          const float yb = acc[h][g][i][j] + bias[col + j];
          const float cl = fminf(fmaxf(yb, -1.0f), 1.0f);
          const float t7 = cl * 7.0f;
          const float rr = rintf(t7);
          const float q = rr / 7.0f;
          op[j] = yb + (q - yb);
        }
        *(float4*)&out[row * N_DIM + col] = o;
      }
    }
}

extern "C" void kernel_launch(void* const* d_in, const int* in_sizes, int n_in,
                              void* d_out, int out_size, void* d_ws, size_t ws_size,
                              hipStream_t stream) {
  const float* x = (const float*)d_in[0];
  const float* w = (const float*)d_in[1];
  const float* bias = (const float*)d_in[2];
  float* out = (float*)d_out;
  float* ws = (float*)d_ws;

  const int M = in_sizes[0] / K_DIM;  // 65536 rows

  leaf_kernel<<<NLEAF / 256, 256, 0, stream>>>(w, ws);
  tree_kernel<<<1, 256, 0, stream>>>(ws);

  const size_t need = (size_t)(WS_EFF + K_DIM * N_DIM) * sizeof(float);  // ~1.06 MB
  if (ws_size >= need) {
    binarize_kernel<<<(K_DIM * N_DIM) / (256 * 4), 256, 0, stream>>>(w, ws);
    gemm_kernel_pre<<<dim3(M / BM, N_DIM / BN), 256, 0, stream>>>(
        x, ws + WS_EFF, bias, out);
  } else {
    gemm_kernel_fused<<<dim3(M / BM, N_DIM / BN), 256, 0, stream>>>(
        x, w, bias, ws, out);
  }
}